// Round 3
// baseline (248.073 us; speedup 1.0000x reference)
//
#include <hip/hip_runtime.h>
#include <math.h>

// Problem constants (match reference)
#define NROWS 8192
#define DDIM  64
#define D4    16      // DDIM / 4 (float4 chunks)

#define RT     256    // rows per block (4 waves x 64 lanes)
#define JT     64     // j-rows staged per LDS stage
#define JSPLIT 32     // grid.y: j-range splits

// ---------------- prep: h[i] = 0.5 * sum_d enc[i,d]^2 ----------------
__global__ void prep_h_kernel(const float* __restrict__ enc, float* __restrict__ h) {
    int wave = threadIdx.x >> 6;
    int lane = threadIdx.x & 63;
    int row  = blockIdx.x * 4 + wave;          // 256 thr = 4 waves = 4 rows/block
    float v  = enc[row * DDIM + lane];
    float sq = v * v;
    #pragma unroll
    for (int off = 32; off > 0; off >>= 1) sq += __shfl_down(sq, off, 64);
    if (lane == 0) h[row] = 0.5f * sq;
}

// ---------------- MSE partial: atomicAdd sum((yp-yt)^2) ----------------
__global__ void mse_kernel(const float* __restrict__ yt, const float* __restrict__ yp,
                           float* __restrict__ acc) {
    int idx = blockIdx.x * blockDim.x + threadIdx.x;   // 131072 threads, 1 float4 each
    const float4* t4 = (const float4*)yt;
    const float4* p4 = (const float4*)yp;
    float4 a = t4[idx], b = p4[idx];
    float dx = b.x - a.x, dy = b.y - a.y, dz = b.z - a.z, dw = b.w - a.w;
    float s = dx*dx + dy*dy + dz*dz + dw*dw;
    #pragma unroll
    for (int off = 32; off > 0; off >>= 1) s += __shfl_down(s, off, 64);
    __shared__ float ls[4];
    int lane = threadIdx.x & 63, w = threadIdx.x >> 6;
    if (lane == 0) ls[w] = s;
    __syncthreads();
    if (threadIdx.x == 0) atomicAdd(acc, ls[0] + ls[1] + ls[2] + ls[3]);
}

// ---------------- pairwise: sum_s[i] += sum_j exp(min(dot - h_i - h_j, 0)) ----------------
__global__ __launch_bounds__(256, 4)
void pairwise_kernel(const float* __restrict__ enc, const float* __restrict__ h,
                     float* __restrict__ sum_s) {
    __shared__ float4 bt[JT * D4];   // 16 KB staged j-tile
    __shared__ float  hj[JT];

    int lane = threadIdx.x & 63;
    int wave = threadIdx.x >> 6;
    int row  = blockIdx.x * RT + wave * 64 + lane;

    // lane-resident row: 16 float4 = 64 VGPR
    const float4* enc4 = (const float4*)enc;
    float4 a[D4];
    #pragma unroll
    for (int k = 0; k < D4; ++k) a[k] = enc4[row * D4 + k];
    float hi = h[row];

    float srow = 0.0f;
    const int jspan = NROWS / JSPLIT;            // 256 j's per block
    const int j0    = blockIdx.y * jspan;

    for (int js = 0; js < jspan; js += JT) {
        int jbase = j0 + js;
        __syncthreads();
        // stage JT rows (coalesced): 1024 float4 by 256 threads
        #pragma unroll
        for (int u = 0; u < 4; ++u) {
            int t = threadIdx.x + u * 256;
            bt[t] = enc4[(jbase + (t >> 4)) * D4 + (t & 15)];
        }
        if (threadIdx.x < JT) hj[threadIdx.x] = h[jbase + threadIdx.x];
        __syncthreads();

        for (int jj = 0; jj < JT; ++jj) {
            float4 acc = make_float4(0.f, 0.f, 0.f, 0.f);  // 4 independent chains
            #pragma unroll
            for (int k = 0; k < D4; ++k) {
                float4 b = bt[jj * D4 + k];                // broadcast ds_read_b128
                acc.x = fmaf(a[k].x, b.x, acc.x);
                acc.y = fmaf(a[k].y, b.y, acc.y);
                acc.z = fmaf(a[k].z, b.z, acc.z);
                acc.w = fmaf(a[k].w, b.w, acc.w);
            }
            float dot = (acc.x + acc.y) + (acc.z + acc.w);
            float arg = dot - hi - hj[jj];                 // = -0.5*d2
            arg = fminf(arg, 0.0f);                        // d2 = max(d2, 0)
            srow += __expf(arg);
        }
    }
    atomicAdd(&sum_s[row], srow);
}

// ---------------- finalize: log per row, means, outputs ----------------
__global__ void finalize_kernel(const float* __restrict__ sum_s,
                                const float* __restrict__ mse_acc,
                                float* __restrict__ out) {
    __shared__ float red[16];
    float s = 0.0f;
    #pragma unroll
    for (int u = 0; u < 8; ++u) s += logf(sum_s[threadIdx.x * 8 + u]);
    #pragma unroll
    for (int off = 32; off > 0; off >>= 1) s += __shfl_down(s, off, 64);
    int lane = threadIdx.x & 63, w = threadIdx.x >> 6;
    if (lane == 0) red[w] = s;
    __syncthreads();
    if (threadIdx.x == 0) {
        float tot = 0.0f;
        #pragma unroll
        for (int i = 0; i < 16; ++i) tot += red[i];
        float kde = tot / (float)NROWS;                       // mean log-sum-exp
        float c   = logf((float)NROWS);
        float IXT = (c - kde) / logf(2.0f);
        float mse = *mse_acc / (float)(NROWS * DDIM);
        out[0] = 1.0f * IXT + 500.0f * mse;   // loss
        out[1] = IXT;
        out[2] = mse;
    }
}

extern "C" void kernel_launch(void* const* d_in, const int* in_sizes, int n_in,
                              void* d_out, int out_size, void* d_ws, size_t ws_size,
                              hipStream_t stream) {
    const float* y_true  = (const float*)d_in[0];
    const float* y_pred  = (const float*)d_in[1];
    const float* encoded = (const float*)d_in[2];
    float* out = (float*)d_out;

    // ws layout: [0] mse_acc | [16..16+8192) h | [16+8192 .. 16+16384) sum_s
    float* wsf     = (float*)d_ws;
    float* mse_acc = wsf;
    float* h       = wsf + 16;
    float* sum_s   = wsf + 16 + NROWS;

    hipMemsetAsync(d_ws, 0, (16 + 2 * NROWS) * sizeof(float), stream);

    prep_h_kernel<<<NROWS / 4, 256, 0, stream>>>(encoded, h);
    mse_kernel<<<(NROWS * DDIM / 4) / 256, 256, 0, stream>>>(y_true, y_pred, mse_acc);
    pairwise_kernel<<<dim3(NROWS / RT, JSPLIT), 256, 0, stream>>>(encoded, h, sum_s);
    finalize_kernel<<<1, 1024, 0, stream>>>(sum_s, mse_acc, out);
}

// Round 4
// 184.230 us; speedup vs baseline: 1.3465x; 1.3465x over previous
//
#include <hip/hip_runtime.h>
#include <math.h>

#define NROWS 8192
#define DDIM  64
#define JSPLIT 32
#define JSPAN  (NROWS / JSPLIT)   // 256

typedef __bf16 bf16x8 __attribute__((ext_vector_type(8)));
typedef float  f32x4  __attribute__((ext_vector_type(4)));

// ws layout (floats): [0] mse_acc | [16, 16+8192) sum_s | [16+8192, 16+16384) hp
// then E_bf (__bf16) at float offset 16+16384  (byte 65600, 16B aligned)

// ---- k1: fused convert(E->bf16) + MSE partial + h-from-diagonal-MFMA ----
__global__ __launch_bounds__(256)
void prep_kernel(const float* __restrict__ yt, const float* __restrict__ yp,
                 const float* __restrict__ enc,
                 __bf16* __restrict__ ebf, float* __restrict__ hp,
                 float* __restrict__ mse_acc) {
    int bid = blockIdx.x;
    int t   = threadIdx.x;
    if (bid < 256) {
        // ---- convert: 8 consecutive floats -> 8 bf16 per thread ----
        int off = bid * 2048 + t * 8;
        const float4* e4 = (const float4*)(enc + off);
        float4 x = e4[0], y = e4[1];
        bf16x8 v;
        v[0]=(__bf16)x.x; v[1]=(__bf16)x.y; v[2]=(__bf16)x.z; v[3]=(__bf16)x.w;
        v[4]=(__bf16)y.x; v[5]=(__bf16)y.y; v[6]=(__bf16)y.z; v[7]=(__bf16)y.w;
        *(bf16x8*)(ebf + off) = v;
    } else if (bid < 768) {
        // ---- MSE partial ----
        int idx = (bid - 256) * 256 + t;           // 512 blocks cover 131072 float4
        const float4* t4 = (const float4*)yt;
        const float4* p4 = (const float4*)yp;
        float4 a = t4[idx], b = p4[idx];
        float dx=b.x-a.x, dy=b.y-a.y, dz=b.z-a.z, dw=b.w-a.w;
        float s = dx*dx + dy*dy + dz*dz + dw*dw;
        #pragma unroll
        for (int off = 32; off > 0; off >>= 1) s += __shfl_down(s, off, 64);
        __shared__ float ls[4];
        int lane = t & 63, w = t >> 6;
        if (lane == 0) ls[w] = s;
        __syncthreads();
        if (t == 0) atomicAdd(mse_acc, ls[0] + ls[1] + ls[2] + ls[3]);
    } else {
        // ---- hp: diagonal-tile MFMA; convert fp32 in-register (bit-identical
        //      to stored ebf) so the pairwise kernel's I==J tiles reproduce
        //      this acc bitwise -> diagonal arg is exactly 0. ----
        int wv = t >> 6, ln = t & 63;
        int tile = (bid - 768) * 4 + wv;           // 0..511
        int lm = ln & 15, lk = ln >> 4;
        const float* r = enc + (tile * 16 + lm) * DDIM;
        bf16x8 f0, f1;
        {
            const float4* q = (const float4*)(r + lk * 8);
            float4 x = q[0], y = q[1];
            f0[0]=(__bf16)x.x; f0[1]=(__bf16)x.y; f0[2]=(__bf16)x.z; f0[3]=(__bf16)x.w;
            f0[4]=(__bf16)y.x; f0[5]=(__bf16)y.y; f0[6]=(__bf16)y.z; f0[7]=(__bf16)y.w;
        }
        {
            const float4* q = (const float4*)(r + 32 + lk * 8);
            float4 x = q[0], y = q[1];
            f1[0]=(__bf16)x.x; f1[1]=(__bf16)x.y; f1[2]=(__bf16)x.z; f1[3]=(__bf16)x.w;
            f1[4]=(__bf16)y.x; f1[5]=(__bf16)y.y; f1[6]=(__bf16)y.z; f1[7]=(__bf16)y.w;
        }
        f32x4 acc = {0.f, 0.f, 0.f, 0.f};
        acc = __builtin_amdgcn_mfma_f32_16x16x32_bf16(f0, f0, acc, 0, 0, 0);
        acc = __builtin_amdgcn_mfma_f32_16x16x32_bf16(f1, f1, acc, 0, 0, 0);
        #pragma unroll
        for (int reg = 0; reg < 4; ++reg) {
            int rc = lk * 4 + reg;                 // C-layout row
            if (lm == rc) hp[tile * 16 + rc] = 0.5f * acc[reg];
        }
    }
}

// ---- k2: pairwise tiles via MFMA; per-lane exp accumulators over j sweep ----
__global__ __launch_bounds__(256, 4)
void pairwise_kernel(const __bf16* __restrict__ ebf, const float* __restrict__ hp,
                     float* __restrict__ sum_s) {
    int t  = threadIdx.x;
    int wv = t >> 6, ln = t & 63;
    int lm = ln & 15, lk = ln >> 4;
    int I0 = (blockIdx.x * 4 + wv) * 64;          // wave's 64-row strip
    int j0 = blockIdx.y * JSPAN;

    // A fragments for 4 m-tiles (held in regs for the whole sweep) + hi
    bf16x8 a[4][2];
    float  hi[16];
    #pragma unroll
    for (int mt = 0; mt < 4; ++mt) {
        const __bf16* rp = ebf + (I0 + mt * 16 + lm) * DDIM + lk * 8;
        a[mt][0] = *(const bf16x8*)(rp);
        a[mt][1] = *(const bf16x8*)(rp + 32);
        #pragma unroll
        for (int reg = 0; reg < 4; ++reg)
            hi[mt * 4 + reg] = hp[I0 + mt * 16 + lk * 4 + reg];
    }
    float eacc[16];
    #pragma unroll
    for (int i = 0; i < 16; ++i) eacc[i] = 0.f;

    for (int js = 0; js < JSPAN; js += 16) {
        int Jt = j0 + js;
        const __bf16* rp = ebf + (Jt + lm) * DDIM + lk * 8;
        bf16x8 b0 = *(const bf16x8*)(rp);
        bf16x8 b1 = *(const bf16x8*)(rp + 32);
        float  hj = hp[Jt + lm];
        #pragma unroll
        for (int mt = 0; mt < 4; ++mt) {
            f32x4 acc = {0.f, 0.f, 0.f, 0.f};
            acc = __builtin_amdgcn_mfma_f32_16x16x32_bf16(a[mt][0], b0, acc, 0, 0, 0);
            acc = __builtin_amdgcn_mfma_f32_16x16x32_bf16(a[mt][1], b1, acc, 0, 0, 0);
            #pragma unroll
            for (int reg = 0; reg < 4; ++reg) {
                float arg = acc[reg] - hi[mt * 4 + reg] - hj;  // = -0.5*d2 (perm'd)
                arg = fminf(arg, 0.f);                          // d2 = max(d2,0)
                eacc[mt * 4 + reg] += __expf(arg);
            }
        }
    }
    // reduce each row-accumulator across the 16 lanes of its column group
    #pragma unroll
    for (int i = 0; i < 16; ++i) {
        float v = eacc[i];
        v += __shfl_xor(v, 1, 64);
        v += __shfl_xor(v, 2, 64);
        v += __shfl_xor(v, 4, 64);
        v += __shfl_xor(v, 8, 64);
        if (lm == 0) {
            int mt = i >> 2, reg = i & 3;
            atomicAdd(&sum_s[I0 + mt * 16 + lk * 4 + reg], v);
        }
    }
}

// ---- k3: finalize ----
__global__ void finalize_kernel(const float* __restrict__ sum_s,
                                const float* __restrict__ mse_acc,
                                float* __restrict__ out) {
    __shared__ float red[16];
    float s = 0.0f;
    #pragma unroll
    for (int u = 0; u < 8; ++u) s += logf(sum_s[threadIdx.x * 8 + u]);
    #pragma unroll
    for (int off = 32; off > 0; off >>= 1) s += __shfl_down(s, off, 64);
    int lane = threadIdx.x & 63, w = threadIdx.x >> 6;
    if (lane == 0) red[w] = s;
    __syncthreads();
    if (threadIdx.x == 0) {
        float tot = 0.0f;
        #pragma unroll
        for (int i = 0; i < 16; ++i) tot += red[i];
        float kde = tot / (float)NROWS;
        float c   = logf((float)NROWS);
        float IXT = (c - kde) / logf(2.0f);
        float mse = *mse_acc / (float)(NROWS * DDIM);
        out[0] = 1.0f * IXT + 500.0f * mse;
        out[1] = IXT;
        out[2] = mse;
    }
}

extern "C" void kernel_launch(void* const* d_in, const int* in_sizes, int n_in,
                              void* d_out, int out_size, void* d_ws, size_t ws_size,
                              hipStream_t stream) {
    const float* y_true  = (const float*)d_in[0];
    const float* y_pred  = (const float*)d_in[1];
    const float* encoded = (const float*)d_in[2];
    float* out = (float*)d_out;

    float*  wsf     = (float*)d_ws;
    float*  mse_acc = wsf;
    float*  sum_s   = wsf + 16;
    float*  hp      = wsf + 16 + NROWS;
    __bf16* ebf     = (__bf16*)(wsf + 16 + 2 * NROWS);

    // zero only the accumulators (hp and ebf are fully overwritten each call)
    hipMemsetAsync(d_ws, 0, (16 + NROWS) * sizeof(float), stream);

    prep_kernel<<<896, 256, 0, stream>>>(y_true, y_pred, encoded, ebf, hp, mse_acc);
    pairwise_kernel<<<dim3(NROWS / 256, JSPLIT), 256, 0, stream>>>(ebf, hp, sum_s);
    finalize_kernel<<<1, 1024, 0, stream>>>(sum_s, mse_acc, out);
}

// Round 5
// 98.566 us; speedup vs baseline: 2.5168x; 1.8691x over previous
//
#include <hip/hip_runtime.h>
#include <math.h>

#define NROWS 8192
#define DDIM  64
#define JSPLIT 32
#define JSPAN  (NROWS / JSPLIT)   // 256

typedef __bf16 bf16x8 __attribute__((ext_vector_type(8)));
typedef float  f32x4  __attribute__((ext_vector_type(4)));

// ws layout (floats): [0] mse_acc | [16, 16+8192) sum_s | [16+8192, 16+16384) hp
// then E_bf (__bf16) at float offset 16+16384  (byte 65600, 16B aligned)

// ---- k1: fused convert(E->bf16) + MSE partial + h-from-diagonal-MFMA ----
__global__ __launch_bounds__(256)
void prep_kernel(const float* __restrict__ yt, const float* __restrict__ yp,
                 const float* __restrict__ enc,
                 __bf16* __restrict__ ebf, float* __restrict__ hp,
                 float* __restrict__ mse_acc) {
    int bid = blockIdx.x;
    int t   = threadIdx.x;
    if (bid < 256) {
        // ---- convert: 8 consecutive floats -> 8 bf16 per thread ----
        int off = bid * 2048 + t * 8;
        const float4* e4 = (const float4*)(enc + off);
        float4 x = e4[0], y = e4[1];
        bf16x8 v;
        v[0]=(__bf16)x.x; v[1]=(__bf16)x.y; v[2]=(__bf16)x.z; v[3]=(__bf16)x.w;
        v[4]=(__bf16)y.x; v[5]=(__bf16)y.y; v[6]=(__bf16)y.z; v[7]=(__bf16)y.w;
        *(bf16x8*)(ebf + off) = v;
    } else if (bid < 768) {
        // ---- MSE partial ----
        int idx = (bid - 256) * 256 + t;           // 512 blocks cover 131072 float4
        const float4* t4 = (const float4*)yt;
        const float4* p4 = (const float4*)yp;
        float4 a = t4[idx], b = p4[idx];
        float dx=b.x-a.x, dy=b.y-a.y, dz=b.z-a.z, dw=b.w-a.w;
        float s = dx*dx + dy*dy + dz*dz + dw*dw;
        #pragma unroll
        for (int off = 32; off > 0; off >>= 1) s += __shfl_down(s, off, 64);
        __shared__ float ls[4];
        int lane = t & 63, w = t >> 6;
        if (lane == 0) ls[w] = s;
        __syncthreads();
        if (t == 0) atomicAdd(mse_acc, ls[0] + ls[1] + ls[2] + ls[3]);
    } else {
        // ---- hp: diagonal-tile MFMA; convert fp32 in-register (bit-identical
        //      to stored ebf) so the pairwise kernel's I==J tiles reproduce
        //      this acc (up to MFMA C-seed reassociation, |err| <= |acc|*2^-20). ----
        int wv = t >> 6, ln = t & 63;
        int tile = (bid - 768) * 4 + wv;           // 0..511
        int lm = ln & 15, lk = ln >> 4;
        const float* r = enc + (tile * 16 + lm) * DDIM;
        bf16x8 f0, f1;
        {
            const float4* q = (const float4*)(r + lk * 8);
            float4 x = q[0], y = q[1];
            f0[0]=(__bf16)x.x; f0[1]=(__bf16)x.y; f0[2]=(__bf16)x.z; f0[3]=(__bf16)x.w;
            f0[4]=(__bf16)y.x; f0[5]=(__bf16)y.y; f0[6]=(__bf16)y.z; f0[7]=(__bf16)y.w;
        }
        {
            const float4* q = (const float4*)(r + 32 + lk * 8);
            float4 x = q[0], y = q[1];
            f1[0]=(__bf16)x.x; f1[1]=(__bf16)x.y; f1[2]=(__bf16)x.z; f1[3]=(__bf16)x.w;
            f1[4]=(__bf16)y.x; f1[5]=(__bf16)y.y; f1[6]=(__bf16)y.z; f1[7]=(__bf16)y.w;
        }
        f32x4 acc = {0.f, 0.f, 0.f, 0.f};
        acc = __builtin_amdgcn_mfma_f32_16x16x32_bf16(f0, f0, acc, 0, 0, 0);
        acc = __builtin_amdgcn_mfma_f32_16x16x32_bf16(f1, f1, acc, 0, 0, 0);
        #pragma unroll
        for (int reg = 0; reg < 4; ++reg) {
            int rc = lk * 4 + reg;                 // C-layout row
            if (lm == rc) hp[tile * 16 + rc] = 0.5f * acc[reg];
        }
    }
}

// ---- k2: pairwise tiles via MFMA; per-lane exp accumulators over j sweep ----
// amdgpu_waves_per_eu(1,4): cap at 4 waves/EU -> 128-VGPR budget. Round-4's
// __launch_bounds__(256,4) let the scheduler aim 8 waves/EU (64-VGPR budget)
// and spill/sink ~40 regs of loop state to scratch -> 475 MB HBM per dispatch.
__global__ __launch_bounds__(256)
__attribute__((amdgpu_waves_per_eu(1, 4)))
void pairwise_kernel(const __bf16* __restrict__ ebf, const float* __restrict__ hp,
                     float* __restrict__ sum_s) {
    int t  = threadIdx.x;
    int wv = t >> 6, ln = t & 63;
    int lm = ln & 15, lk = ln >> 4;
    int I0 = (blockIdx.x * 4 + wv) * 64;          // wave's 64-row strip
    int j0 = blockIdx.y * JSPAN;

    // A fragments for 4 m-tiles (held in regs for the whole sweep) + hi
    bf16x8 a[4][2];
    float  hi[16];
    #pragma unroll
    for (int mt = 0; mt < 4; ++mt) {
        const __bf16* rp = ebf + (I0 + mt * 16 + lm) * DDIM + lk * 8;
        a[mt][0] = *(const bf16x8*)(rp);
        a[mt][1] = *(const bf16x8*)(rp + 32);
        #pragma unroll
        for (int reg = 0; reg < 4; ++reg)
            hi[mt * 4 + reg] = hp[I0 + mt * 16 + lk * 4 + reg];
    }
    float eacc[16];
    #pragma unroll
    for (int i = 0; i < 16; ++i) eacc[i] = 0.f;

    for (int js = 0; js < JSPAN; js += 16) {
        int Jt = j0 + js;
        const __bf16* rp = ebf + (Jt + lm) * DDIM + lk * 8;
        bf16x8 b0 = *(const bf16x8*)(rp);
        bf16x8 b1 = *(const bf16x8*)(rp + 32);
        float  nhj = -hp[Jt + lm];
        #pragma unroll
        for (int mt = 0; mt < 4; ++mt) {
            // seed C with -(hi+hj): epilogue becomes min+exp+add only
            f32x4 acc = {nhj - hi[mt * 4 + 0], nhj - hi[mt * 4 + 1],
                         nhj - hi[mt * 4 + 2], nhj - hi[mt * 4 + 3]};
            acc = __builtin_amdgcn_mfma_f32_16x16x32_bf16(a[mt][0], b0, acc, 0, 0, 0);
            acc = __builtin_amdgcn_mfma_f32_16x16x32_bf16(a[mt][1], b1, acc, 0, 0, 0);
            #pragma unroll
            for (int reg = 0; reg < 4; ++reg) {
                float arg = fminf(acc[reg], 0.f);               // d2 = max(d2,0)
                eacc[mt * 4 + reg] += __expf(arg);
            }
        }
    }
    // reduce each row-accumulator across the 16 lanes of its column group
    #pragma unroll
    for (int i = 0; i < 16; ++i) {
        float v = eacc[i];
        v += __shfl_xor(v, 1, 64);
        v += __shfl_xor(v, 2, 64);
        v += __shfl_xor(v, 4, 64);
        v += __shfl_xor(v, 8, 64);
        if (lm == 0) {
            int mt = i >> 2, reg = i & 3;
            atomicAdd(&sum_s[I0 + mt * 16 + lk * 4 + reg], v);
        }
    }
}

// ---- k3: finalize ----
__global__ void finalize_kernel(const float* __restrict__ sum_s,
                                const float* __restrict__ mse_acc,
                                float* __restrict__ out) {
    __shared__ float red[16];
    float s = 0.0f;
    #pragma unroll
    for (int u = 0; u < 8; ++u) s += logf(sum_s[threadIdx.x * 8 + u]);
    #pragma unroll
    for (int off = 32; off > 0; off >>= 1) s += __shfl_down(s, off, 64);
    int lane = threadIdx.x & 63, w = threadIdx.x >> 6;
    if (lane == 0) red[w] = s;
    __syncthreads();
    if (threadIdx.x == 0) {
        float tot = 0.0f;
        #pragma unroll
        for (int i = 0; i < 16; ++i) tot += red[i];
        float kde = tot / (float)NROWS;
        float c   = logf((float)NROWS);
        float IXT = (c - kde) / logf(2.0f);
        float mse = *mse_acc / (float)(NROWS * DDIM);
        out[0] = 1.0f * IXT + 500.0f * mse;
        out[1] = IXT;
        out[2] = mse;
    }
}

extern "C" void kernel_launch(void* const* d_in, const int* in_sizes, int n_in,
                              void* d_out, int out_size, void* d_ws, size_t ws_size,
                              hipStream_t stream) {
    const float* y_true  = (const float*)d_in[0];
    const float* y_pred  = (const float*)d_in[1];
    const float* encoded = (const float*)d_in[2];
    float* out = (float*)d_out;

    float*  wsf     = (float*)d_ws;
    float*  mse_acc = wsf;
    float*  sum_s   = wsf + 16;
    float*  hp      = wsf + 16 + NROWS;
    __bf16* ebf     = (__bf16*)(wsf + 16 + 2 * NROWS);

    // zero only the accumulators (hp and ebf are fully overwritten each call)
    hipMemsetAsync(d_ws, 0, (16 + NROWS) * sizeof(float), stream);

    prep_kernel<<<896, 256, 0, stream>>>(y_true, y_pred, encoded, ebf, hp, mse_acc);
    pairwise_kernel<<<dim3(NROWS / 256, JSPLIT), 256, 0, stream>>>(ebf, hp, sum_s);
    finalize_kernel<<<1, 1024, 0, stream>>>(sum_s, mse_acc, out);
}

// Round 6
// 89.587 us; speedup vs baseline: 2.7691x; 1.1002x over previous
//
#include <hip/hip_runtime.h>
#include <math.h>

#define NROWS 8192
#define DDIM  64
#define JSPLIT 32
#define JSPAN  (NROWS / JSPLIT)   // 256
#define LOG2E  1.4426950408889634f

typedef __bf16 bf16x8 __attribute__((ext_vector_type(8)));
typedef float  f32x4  __attribute__((ext_vector_type(4)));

// ws layout (floats): [0,512) mse_part | [512, 512+8192) sum_s |
//   [8704, 8704+8192) hp2 | then ebf (bf16, plain) then ebl (bf16, *log2e)

// ---- k1: convert (plain + log2e-scaled) | MSE partials | hp2 diag-MFMA | zero sum_s ----
__global__ __launch_bounds__(256)
void prep_kernel(const float* __restrict__ yt, const float* __restrict__ yp,
                 const float* __restrict__ enc,
                 __bf16* __restrict__ ebf, __bf16* __restrict__ ebl,
                 float* __restrict__ hp2, float* __restrict__ mse_part,
                 float* __restrict__ sum_s) {
    int bid = blockIdx.x;
    int t   = threadIdx.x;
    if (bid < 256) {
        // convert 8 floats/thread -> bf16 plain and bf16*log2e
        int off = bid * 2048 + t * 8;
        const float4* e4 = (const float4*)(enc + off);
        float4 x = e4[0], y = e4[1];
        bf16x8 v, w;
        v[0]=(__bf16)x.x; v[1]=(__bf16)x.y; v[2]=(__bf16)x.z; v[3]=(__bf16)x.w;
        v[4]=(__bf16)y.x; v[5]=(__bf16)y.y; v[6]=(__bf16)y.z; v[7]=(__bf16)y.w;
        w[0]=(__bf16)(x.x*LOG2E); w[1]=(__bf16)(x.y*LOG2E);
        w[2]=(__bf16)(x.z*LOG2E); w[3]=(__bf16)(x.w*LOG2E);
        w[4]=(__bf16)(y.x*LOG2E); w[5]=(__bf16)(y.y*LOG2E);
        w[6]=(__bf16)(y.z*LOG2E); w[7]=(__bf16)(y.w*LOG2E);
        *(bf16x8*)(ebf + off) = v;
        *(bf16x8*)(ebl + off) = w;
    } else if (bid < 768) {
        // MSE partial -> WRITE (no atomic, no pre-zero needed)
        int idx = (bid - 256) * 256 + t;
        const float4* t4 = (const float4*)yt;
        const float4* p4 = (const float4*)yp;
        float4 a = t4[idx], b = p4[idx];
        float dx=b.x-a.x, dy=b.y-a.y, dz=b.z-a.z, dw=b.w-a.w;
        float s = dx*dx + dy*dy + dz*dz + dw*dw;
        #pragma unroll
        for (int off = 32; off > 0; off >>= 1) s += __shfl_down(s, off, 64);
        __shared__ float ls[4];
        int lane = t & 63, w = t >> 6;
        if (lane == 0) ls[w] = s;
        __syncthreads();
        if (t == 0) mse_part[bid - 256] = ls[0] + ls[1] + ls[2] + ls[3];
    } else if (bid < 896) {
        // hp2 from diagonal tile: plain(A) x scaled(B) MFMA, same as pairwise
        int wv = t >> 6, ln = t & 63;
        int tile = (bid - 768) * 4 + wv;           // 0..511
        int lm = ln & 15, lk = ln >> 4;
        const float* r = enc + (tile * 16 + lm) * DDIM;
        bf16x8 f0, f1, g0, g1;
        {
            const float4* q = (const float4*)(r + lk * 8);
            float4 x = q[0], y = q[1];
            f0[0]=(__bf16)x.x; f0[1]=(__bf16)x.y; f0[2]=(__bf16)x.z; f0[3]=(__bf16)x.w;
            f0[4]=(__bf16)y.x; f0[5]=(__bf16)y.y; f0[6]=(__bf16)y.z; f0[7]=(__bf16)y.w;
            g0[0]=(__bf16)(x.x*LOG2E); g0[1]=(__bf16)(x.y*LOG2E);
            g0[2]=(__bf16)(x.z*LOG2E); g0[3]=(__bf16)(x.w*LOG2E);
            g0[4]=(__bf16)(y.x*LOG2E); g0[5]=(__bf16)(y.y*LOG2E);
            g0[6]=(__bf16)(y.z*LOG2E); g0[7]=(__bf16)(y.w*LOG2E);
        }
        {
            const float4* q = (const float4*)(r + 32 + lk * 8);
            float4 x = q[0], y = q[1];
            f1[0]=(__bf16)x.x; f1[1]=(__bf16)x.y; f1[2]=(__bf16)x.z; f1[3]=(__bf16)x.w;
            f1[4]=(__bf16)y.x; f1[5]=(__bf16)y.y; f1[6]=(__bf16)y.z; f1[7]=(__bf16)y.w;
            g1[0]=(__bf16)(x.x*LOG2E); g1[1]=(__bf16)(x.y*LOG2E);
            g1[2]=(__bf16)(x.z*LOG2E); g1[3]=(__bf16)(x.w*LOG2E);
            g1[4]=(__bf16)(y.x*LOG2E); g1[5]=(__bf16)(y.y*LOG2E);
            g1[6]=(__bf16)(y.z*LOG2E); g1[7]=(__bf16)(y.w*LOG2E);
        }
        f32x4 acc = {0.f, 0.f, 0.f, 0.f};
        acc = __builtin_amdgcn_mfma_f32_16x16x32_bf16(f0, g0, acc, 0, 0, 0);
        acc = __builtin_amdgcn_mfma_f32_16x16x32_bf16(f1, g1, acc, 0, 0, 0);
        #pragma unroll
        for (int reg = 0; reg < 4; ++reg) {
            int rc = lk * 4 + reg;
            if (lm == rc) hp2[tile * 16 + rc] = 0.5f * acc[reg];
        }
    } else {
        // zero sum_s: bid 896..899, 4 blocks x 256 thr x 8 floats
        int off = (bid - 896) * 2048 + t * 8;
        float4 z = make_float4(0.f, 0.f, 0.f, 0.f);
        ((float4*)(sum_s + off))[0] = z;
        ((float4*)(sum_s + off))[1] = z;
    }
}

// ---- k2: pairwise MFMA + exp2 accumulate (args pre-scaled by log2e) ----
__global__ __launch_bounds__(256)
__attribute__((amdgpu_waves_per_eu(1, 4)))
void pairwise_kernel(const __bf16* __restrict__ ebf, const __bf16* __restrict__ ebl,
                     const float* __restrict__ hp2, float* __restrict__ sum_s) {
    int t  = threadIdx.x;
    int wv = t >> 6, ln = t & 63;
    int lm = ln & 15, lk = ln >> 4;
    int I0 = (blockIdx.x * 4 + wv) * 64;
    int j0 = blockIdx.y * JSPAN;

    bf16x8 a[4][2];
    float  hi2[16];
    #pragma unroll
    for (int mt = 0; mt < 4; ++mt) {
        const __bf16* rp = ebf + (I0 + mt * 16 + lm) * DDIM + lk * 8;
        a[mt][0] = *(const bf16x8*)(rp);
        a[mt][1] = *(const bf16x8*)(rp + 32);
        #pragma unroll
        for (int reg = 0; reg < 4; ++reg)
            hi2[mt * 4 + reg] = hp2[I0 + mt * 16 + lk * 4 + reg];
    }
    float eacc[16];
    #pragma unroll
    for (int i = 0; i < 16; ++i) eacc[i] = 0.f;

    for (int js = 0; js < JSPAN; js += 16) {
        int Jt = j0 + js;
        const __bf16* rp = ebl + (Jt + lm) * DDIM + lk * 8;
        bf16x8 b0 = *(const bf16x8*)(rp);
        bf16x8 b1 = *(const bf16x8*)(rp + 32);
        float  nhj = -hp2[Jt + lm];
        #pragma unroll
        for (int mt = 0; mt < 4; ++mt) {
            f32x4 acc = {nhj - hi2[mt * 4 + 0], nhj - hi2[mt * 4 + 1],
                         nhj - hi2[mt * 4 + 2], nhj - hi2[mt * 4 + 3]};
            acc = __builtin_amdgcn_mfma_f32_16x16x32_bf16(a[mt][0], b0, acc, 0, 0, 0);
            acc = __builtin_amdgcn_mfma_f32_16x16x32_bf16(a[mt][1], b1, acc, 0, 0, 0);
            #pragma unroll
            for (int reg = 0; reg < 4; ++reg)
                eacc[mt * 4 + reg] += __builtin_amdgcn_exp2f(acc[reg]);
        }
    }
    #pragma unroll
    for (int i = 0; i < 16; ++i) {
        float v = eacc[i];
        v += __shfl_xor(v, 1, 64);
        v += __shfl_xor(v, 2, 64);
        v += __shfl_xor(v, 4, 64);
        v += __shfl_xor(v, 8, 64);
        if (lm == 0) {
            int mt = i >> 2, reg = i & 3;
            atomicAdd(&sum_s[I0 + mt * 16 + lk * 4 + reg], v);
        }
    }
}

// ---- k3: finalize (log-mean + mse partial sum + outputs) ----
__global__ __launch_bounds__(1024)
void finalize_kernel(const float* __restrict__ sum_s,
                     const float* __restrict__ mse_part,
                     float* __restrict__ out) {
    int t = threadIdx.x, lane = t & 63, w = t >> 6;
    float s = 0.0f;
    #pragma unroll
    for (int u = 0; u < 8; ++u) s += logf(sum_s[t * 8 + u]);
    float m = (t < 512) ? mse_part[t] : 0.f;
    #pragma unroll
    for (int off = 32; off > 0; off >>= 1) {
        s += __shfl_down(s, off, 64);
        m += __shfl_down(m, off, 64);
    }
    __shared__ float rs[16], rm[16];
    if (lane == 0) { rs[w] = s; rm[w] = m; }
    __syncthreads();
    if (t == 0) {
        float tot = 0.f, mtot = 0.f;
        #pragma unroll
        for (int i = 0; i < 16; ++i) { tot += rs[i]; mtot += rm[i]; }
        float kde = tot / (float)NROWS;
        float c   = logf((float)NROWS);
        float IXT = (c - kde) / logf(2.0f);
        float mse = mtot / (float)(NROWS * DDIM);
        out[0] = 1.0f * IXT + 500.0f * mse;
        out[1] = IXT;
        out[2] = mse;
    }
}

extern "C" void kernel_launch(void* const* d_in, const int* in_sizes, int n_in,
                              void* d_out, int out_size, void* d_ws, size_t ws_size,
                              hipStream_t stream) {
    const float* y_true  = (const float*)d_in[0];
    const float* y_pred  = (const float*)d_in[1];
    const float* encoded = (const float*)d_in[2];
    float* out = (float*)d_out;

    float*  wsf      = (float*)d_ws;
    float*  mse_part = wsf;                        // 512
    float*  sum_s    = wsf + 512;                  // 8192
    float*  hp2      = wsf + 512 + NROWS;          // 8192
    __bf16* ebf      = (__bf16*)(wsf + 512 + 2 * NROWS);
    __bf16* ebl      = ebf + NROWS * DDIM;

    prep_kernel<<<900, 256, 0, stream>>>(y_true, y_pred, encoded,
                                         ebf, ebl, hp2, mse_part, sum_s);
    pairwise_kernel<<<dim3(NROWS / 256, JSPLIT), 256, 0, stream>>>(ebf, ebl, hp2, sum_s);
    finalize_kernel<<<1, 1024, 0, stream>>>(sum_s, mse_part, out);
}

// Round 7
// 87.258 us; speedup vs baseline: 2.8430x; 1.0267x over previous
//
#include <hip/hip_runtime.h>
#include <math.h>

#define NROWS 8192
#define DDIM  64
#define JSPLIT 32
#define JSPAN  (NROWS / JSPLIT)   // 256
#define LOG2E  1.4426950408889634f
#define SKIP_THR (-28.0f)         // exp2(-28)*8192 = 3e-5 on a sum >= 1

typedef __bf16 bf16x8 __attribute__((ext_vector_type(8)));
typedef float  f32x4  __attribute__((ext_vector_type(4)));

// ws layout (floats): [0,512) mse_part | [512, 512+8192) sum_s |
//   [8704, 8704+8192) hp2 | then ebf (bf16, plain) then ebl (bf16, *log2e)

// ---- k1: convert (plain + log2e-scaled) | MSE partials | hp2 diag-MFMA | zero sum_s ----
__global__ __launch_bounds__(256)
void prep_kernel(const float* __restrict__ yt, const float* __restrict__ yp,
                 const float* __restrict__ enc,
                 __bf16* __restrict__ ebf, __bf16* __restrict__ ebl,
                 float* __restrict__ hp2, float* __restrict__ mse_part,
                 float* __restrict__ sum_s) {
    int bid = blockIdx.x;
    int t   = threadIdx.x;
    if (bid < 256) {
        int off = bid * 2048 + t * 8;
        const float4* e4 = (const float4*)(enc + off);
        float4 x = e4[0], y = e4[1];
        bf16x8 v, w;
        v[0]=(__bf16)x.x; v[1]=(__bf16)x.y; v[2]=(__bf16)x.z; v[3]=(__bf16)x.w;
        v[4]=(__bf16)y.x; v[5]=(__bf16)y.y; v[6]=(__bf16)y.z; v[7]=(__bf16)y.w;
        w[0]=(__bf16)(x.x*LOG2E); w[1]=(__bf16)(x.y*LOG2E);
        w[2]=(__bf16)(x.z*LOG2E); w[3]=(__bf16)(x.w*LOG2E);
        w[4]=(__bf16)(y.x*LOG2E); w[5]=(__bf16)(y.y*LOG2E);
        w[6]=(__bf16)(y.z*LOG2E); w[7]=(__bf16)(y.w*LOG2E);
        *(bf16x8*)(ebf + off) = v;
        *(bf16x8*)(ebl + off) = w;
    } else if (bid < 768) {
        int idx = (bid - 256) * 256 + t;
        const float4* t4 = (const float4*)yt;
        const float4* p4 = (const float4*)yp;
        float4 a = t4[idx], b = p4[idx];
        float dx=b.x-a.x, dy=b.y-a.y, dz=b.z-a.z, dw=b.w-a.w;
        float s = dx*dx + dy*dy + dz*dz + dw*dw;
        #pragma unroll
        for (int off = 32; off > 0; off >>= 1) s += __shfl_down(s, off, 64);
        __shared__ float ls[4];
        int lane = t & 63, w = t >> 6;
        if (lane == 0) ls[w] = s;
        __syncthreads();
        if (t == 0) mse_part[bid - 256] = ls[0] + ls[1] + ls[2] + ls[3];
    } else if (bid < 896) {
        // hp2 from diagonal tile: plain(A) x scaled(B) MFMA, same math as pairwise
        int wv = t >> 6, ln = t & 63;
        int tile = (bid - 768) * 4 + wv;           // 0..511
        int lm = ln & 15, lk = ln >> 4;
        const float* r = enc + (tile * 16 + lm) * DDIM;
        bf16x8 f0, f1, g0, g1;
        {
            const float4* q = (const float4*)(r + lk * 8);
            float4 x = q[0], y = q[1];
            f0[0]=(__bf16)x.x; f0[1]=(__bf16)x.y; f0[2]=(__bf16)x.z; f0[3]=(__bf16)x.w;
            f0[4]=(__bf16)y.x; f0[5]=(__bf16)y.y; f0[6]=(__bf16)y.z; f0[7]=(__bf16)y.w;
            g0[0]=(__bf16)(x.x*LOG2E); g0[1]=(__bf16)(x.y*LOG2E);
            g0[2]=(__bf16)(x.z*LOG2E); g0[3]=(__bf16)(x.w*LOG2E);
            g0[4]=(__bf16)(y.x*LOG2E); g0[5]=(__bf16)(y.y*LOG2E);
            g0[6]=(__bf16)(y.z*LOG2E); g0[7]=(__bf16)(y.w*LOG2E);
        }
        {
            const float4* q = (const float4*)(r + 32 + lk * 8);
            float4 x = q[0], y = q[1];
            f1[0]=(__bf16)x.x; f1[1]=(__bf16)x.y; f1[2]=(__bf16)x.z; f1[3]=(__bf16)x.w;
            f1[4]=(__bf16)y.x; f1[5]=(__bf16)y.y; f1[6]=(__bf16)y.z; f1[7]=(__bf16)y.w;
            g1[0]=(__bf16)(x.x*LOG2E); g1[1]=(__bf16)(x.y*LOG2E);
            g1[2]=(__bf16)(x.z*LOG2E); g1[3]=(__bf16)(x.w*LOG2E);
            g1[4]=(__bf16)(y.x*LOG2E); g1[5]=(__bf16)(y.y*LOG2E);
            g1[6]=(__bf16)(y.z*LOG2E); g1[7]=(__bf16)(y.w*LOG2E);
        }
        f32x4 acc = {0.f, 0.f, 0.f, 0.f};
        acc = __builtin_amdgcn_mfma_f32_16x16x32_bf16(f0, g0, acc, 0, 0, 0);
        acc = __builtin_amdgcn_mfma_f32_16x16x32_bf16(f1, g1, acc, 0, 0, 0);
        #pragma unroll
        for (int reg = 0; reg < 4; ++reg) {
            int rc = lk * 4 + reg;
            if (lm == rc) hp2[tile * 16 + rc] = 0.5f * acc[reg];
        }
    } else {
        int off = (bid - 896) * 2048 + t * 8;
        float4 z = make_float4(0.f, 0.f, 0.f, 0.f);
        ((float4*)(sum_s + off))[0] = z;
        ((float4*)(sum_s + off))[1] = z;
    }
}

// ---- k2: pairwise MFMA; wave-vote skips exp2 for all-negligible tiles ----
__global__ __launch_bounds__(256)
__attribute__((amdgpu_waves_per_eu(1, 4)))
void pairwise_kernel(const __bf16* __restrict__ ebf, const __bf16* __restrict__ ebl,
                     const float* __restrict__ hp2, float* __restrict__ sum_s) {
    int t  = threadIdx.x;
    int wv = t >> 6, ln = t & 63;
    int lm = ln & 15, lk = ln >> 4;
    int I0 = (blockIdx.x * 4 + wv) * 64;
    int j0 = blockIdx.y * JSPAN;

    bf16x8 a[4][2];
    float  hi2[16];
    #pragma unroll
    for (int mt = 0; mt < 4; ++mt) {
        const __bf16* rp = ebf + (I0 + mt * 16 + lm) * DDIM + lk * 8;
        a[mt][0] = *(const bf16x8*)(rp);
        a[mt][1] = *(const bf16x8*)(rp + 32);
        #pragma unroll
        for (int reg = 0; reg < 4; ++reg)
            hi2[mt * 4 + reg] = hp2[I0 + mt * 16 + lk * 4 + reg];
    }
    float eacc[16];
    #pragma unroll
    for (int i = 0; i < 16; ++i) eacc[i] = 0.f;

    // software pipeline: prefetch next iteration's B fragments + hj
    const __bf16* rp0 = ebl + (j0 + lm) * DDIM + lk * 8;
    bf16x8 b0 = *(const bf16x8*)(rp0);
    bf16x8 b1 = *(const bf16x8*)(rp0 + 32);
    float  nhj = -hp2[j0 + lm];

    for (int js = 0; js < JSPAN; js += 16) {
        // prefetch next (wrap to j0 on last iter; result unused there)
        int jn = (js + 16 < JSPAN) ? (j0 + js + 16) : j0;
        const __bf16* rpn = ebl + (jn + lm) * DDIM + lk * 8;
        bf16x8 pb0 = *(const bf16x8*)(rpn);
        bf16x8 pb1 = *(const bf16x8*)(rpn + 32);
        float  pnhj = -hp2[jn + lm];

        #pragma unroll
        for (int mt = 0; mt < 4; ++mt) {
            f32x4 acc = {nhj - hi2[mt * 4 + 0], nhj - hi2[mt * 4 + 1],
                         nhj - hi2[mt * 4 + 2], nhj - hi2[mt * 4 + 3]};
            acc = __builtin_amdgcn_mfma_f32_16x16x32_bf16(a[mt][0], b0, acc, 0, 0, 0);
            acc = __builtin_amdgcn_mfma_f32_16x16x32_bf16(a[mt][1], b1, acc, 0, 0, 0);
            // wave-vote: only tiles with any arg > -28 contribute in fp32
            float m = fmaxf(fmaxf(acc[0], acc[1]), fmaxf(acc[2], acc[3]));
            if (__any(m > SKIP_THR)) {
                #pragma unroll
                for (int reg = 0; reg < 4; ++reg)
                    eacc[mt * 4 + reg] += __builtin_amdgcn_exp2f(acc[reg]);
            }
        }
        b0 = pb0; b1 = pb1; nhj = pnhj;
    }
    #pragma unroll
    for (int i = 0; i < 16; ++i) {
        float v = eacc[i];
        v += __shfl_xor(v, 1, 64);
        v += __shfl_xor(v, 2, 64);
        v += __shfl_xor(v, 4, 64);
        v += __shfl_xor(v, 8, 64);
        if (lm == 0) {
            int mt = i >> 2, reg = i & 3;
            atomicAdd(&sum_s[I0 + mt * 16 + lk * 4 + reg], v);
        }
    }
}

// ---- k3: finalize (log-mean + mse partial sum + outputs) ----
__global__ __launch_bounds__(1024)
void finalize_kernel(const float* __restrict__ sum_s,
                     const float* __restrict__ mse_part,
                     float* __restrict__ out) {
    int t = threadIdx.x, lane = t & 63, w = t >> 6;
    float s = 0.0f;
    #pragma unroll
    for (int u = 0; u < 8; ++u) s += __logf(sum_s[t * 8 + u]);
    float m = (t < 512) ? mse_part[t] : 0.f;
    #pragma unroll
    for (int off = 32; off > 0; off >>= 1) {
        s += __shfl_down(s, off, 64);
        m += __shfl_down(m, off, 64);
    }
    __shared__ float rs[16], rm[16];
    if (lane == 0) { rs[w] = s; rm[w] = m; }
    __syncthreads();
    if (t == 0) {
        float tot = 0.f, mtot = 0.f;
        #pragma unroll
        for (int i = 0; i < 16; ++i) { tot += rs[i]; mtot += rm[i]; }
        float kde = tot / (float)NROWS;
        float c   = logf((float)NROWS);
        float IXT = (c - kde) / logf(2.0f);
        float mse = mtot / (float)(NROWS * DDIM);
        out[0] = 1.0f * IXT + 500.0f * mse;
        out[1] = IXT;
        out[2] = mse;
    }
}

extern "C" void kernel_launch(void* const* d_in, const int* in_sizes, int n_in,
                              void* d_out, int out_size, void* d_ws, size_t ws_size,
                              hipStream_t stream) {
    const float* y_true  = (const float*)d_in[0];
    const float* y_pred  = (const float*)d_in[1];
    const float* encoded = (const float*)d_in[2];
    float* out = (float*)d_out;

    float*  wsf      = (float*)d_ws;
    float*  mse_part = wsf;                        // 512
    float*  sum_s    = wsf + 512;                  // 8192
    float*  hp2      = wsf + 512 + NROWS;          // 8192
    __bf16* ebf      = (__bf16*)(wsf + 512 + 2 * NROWS);
    __bf16* ebl      = ebf + NROWS * DDIM;

    prep_kernel<<<900, 256, 0, stream>>>(y_true, y_pred, encoded,
                                         ebf, ebl, hp2, mse_part, sum_s);
    pairwise_kernel<<<dim3(NROWS / 256, JSPLIT), 256, 0, stream>>>(ebf, ebl, hp2, sum_s);
    finalize_kernel<<<1, 1024, 0, stream>>>(sum_s, mse_part, out);
}